// Round 14
// baseline (87.580 us; speedup 1.0000x reference)
//
#include <hip/hip_runtime.h>
#include <cstdint>
#include <cstddef>

#define B 128
#define P 8732
#define NC 21
#define O 16
#define THRESH 0.5f
#define QPI 2183   // quads per image = P/4
#define NBX 18     // pass2 blocks per image (128 quads per block)
#define NPART (B * NBX)
#define NB1 8      // pass1 blocks per image

typedef unsigned long long u64;
typedef unsigned int u32;
typedef unsigned char u8;

__device__ __forceinline__ float iou_pt(float a0, float a1, float a2, float a3,
                                        float b0, float b1, float b2, float b3) {
    float ltx = fmaxf(a0, b0), lty = fmaxf(a1, b1);
    float rbx = fminf(a2, b2), rby = fminf(a3, b3);
    float wx = fmaxf(rbx - ltx, 0.0f), wy = fmaxf(rby - lty, 0.0f);
    float inter = wx * wy;
    float aa = (a2 - a0) * (a3 - a1);
    float ab = (b2 - b0) * (b3 - b1);
    return inter / (aa + ab - inter);
}

// Pass 1: per-object best-prior partial max (plain stores) AND per-prior
// packed best-truth byte: idx | (ov>=THRESH ? 0x80 : 0). Also zeroes the
// hardneg accumulator + ticket (kernel-boundary ordering makes it visible).
__global__ void __launch_bounds__(256) k_pass1(const float* __restrict__ gt,
                                               const float* __restrict__ priors,
                                               u64* __restrict__ bk,
                                               u8* __restrict__ bidx,
                                               double* __restrict__ acc,
                                               u32* __restrict__ ticket) {
    const int b = blockIdx.y;
    __shared__ float s_gt[O * 4];
    __shared__ u64 s_wk[4][O];
    const int tid = threadIdx.x;
    const int wave = tid >> 6, lane = tid & 63;
    if (blockIdx.x == 0 && b == 0 && tid == 0) { acc[0] = 0.0; *ticket = 0u; }
    if (tid < O * 4) {
        int o = tid >> 2, c = tid & 3;
        s_gt[tid] = gt[(b * O + o) * 5 + c];
    }
    __syncthreads();

    u64 lk[O];
#pragma unroll
    for (int o = 0; o < O; o++) lk[o] = 0ull;

    for (int p = blockIdx.x * 256 + tid; p < P; p += NB1 * 256) {
        float4 pr = reinterpret_cast<const float4*>(priors)[p];
        float b0 = pr.x - pr.z * 0.5f, b1 = pr.y - pr.w * 0.5f;
        float b2 = pr.x + pr.z * 0.5f, b3 = pr.y + pr.w * 0.5f;
        float bov = -1.0f; int bo = 0;
#pragma unroll
        for (int o = 0; o < O; o++) {
            float v = iou_pt(s_gt[o * 4 + 0], s_gt[o * 4 + 1], s_gt[o * 4 + 2], s_gt[o * 4 + 3],
                             b0, b1, b2, b3);
            u64 key = ((u64)__float_as_uint(v) << 32) | (u64)(0xFFFFFFFFu - (u32)p);
            lk[o] = (key > lk[o]) ? key : lk[o];
            if (v > bov) { bov = v; bo = o; }   // first occurrence on tie
        }
        bidx[(size_t)b * P + p] = (u8)(bo | ((bov >= THRESH) ? 0x80 : 0));
    }

#pragma unroll
    for (int o = 0; o < O; o++) {
        u64 k = lk[o];
#pragma unroll
        for (int off = 32; off > 0; off >>= 1) {
            u64 other = (u64)__shfl_xor((long long)k, off, 64);
            k = (other > k) ? other : k;
        }
        if (lane == 0) s_wk[wave][o] = k;
    }
    __syncthreads();
    if (tid < O) {
        u64 k = s_wk[0][tid];
#pragma unroll
        for (int w = 1; w < 4; w++) { u64 v = s_wk[w][tid]; k = (v > k) ? v : k; }
        bk[((size_t)b * O + tid) * NB1 + blockIdx.x] = k;
    }
}

// Evaluate one prior whose 21 scores live at fq[OFF..OFF+20] (OFF compile-time).
// Returns the mine value; accumulates pos-path contributions.
template<int OFF>
__device__ __forceinline__ float prior_eval(const float (&fq)[44],
                                            const float* s_gt, const int* s_bp,
                                            int p, int ebyte,
                                            const float* __restrict__ priors,
                                            const float* __restrict__ loc_preds,
                                            size_t lp_base,
                                            float& l_loc, float& l_ce, int& l_np) {
    int best_idx = ebyte & 0x3F;
    bool matched = (ebyte & 0x80) != 0;
#pragma unroll
    for (int o = 0; o < O; o++) {
        if (s_bp[o] == p) { best_idx = o; matched = true; }   // ascending: last wins
    }
    int cls = matched ? (int)s_gt[best_idx * 5 + 4] : 0;

    float mx = fq[OFF];
#pragma unroll
    for (int c = 1; c < NC; c++) mx = fmaxf(mx, fq[OFF + c]);
    float se = 0.0f;
#pragma unroll
    for (int c = 0; c < NC; c++) se += __expf(fq[OFF + c] - mx);
    float lse = mx + __logf(se);
    float g = fq[OFF];
#pragma unroll
    for (int c = 1; c < NC; c++) g = (c == cls) ? fq[OFF + c] : g;
    float ce = lse - g;

    if (matched) {   // matched <=> positive (labels >= 1)
        l_np++;
        l_ce += ce;
        float4 pr = reinterpret_cast<const float4*>(priors)[p];
        float m0 = s_gt[best_idx * 5 + 0], m1 = s_gt[best_idx * 5 + 1];
        float m2 = s_gt[best_idx * 5 + 2], m3 = s_gt[best_idx * 5 + 3];
        float tx = ((m0 + m2) * 0.5f - pr.x) / (0.1f * pr.z);
        float ty = ((m1 + m3) * 0.5f - pr.y) / (0.1f * pr.w);
        float tw = __logf((m2 - m0) / pr.z) * 5.0f;
        float th = __logf((m3 - m1) / pr.w) * 5.0f;
        float4 lp = reinterpret_cast<const float4*>(loc_preds)[lp_base + p];
        float d0 = fabsf(lp.x - tx), d1 = fabsf(lp.y - ty);
        float d2 = fabsf(lp.z - tw), d3 = fabsf(lp.w - th);
        float s0 = d0 < 1.0f ? 0.5f * d0 * d0 : d0 - 0.5f;
        float s1 = d1 < 1.0f ? 0.5f * d1 * d1 : d1 - 0.5f;
        float s2 = d2 < 1.0f ? 0.5f * d2 * d2 : d2 - 0.5f;
        float s3 = d3 < 1.0f ? 0.5f * d3 * d3 : d3 - 0.5f;
        l_loc += (s0 + s1) + (s2 + s3);
        return 0.0f;
    }
    return ce;
}

// Pass 2: 2 priors/thread, 2304 blocks (2x the waves of the 4-prior version).
// Block covers 128 quads; threads 0..127 take the low half (priors 4q,4q+1,
// float4s 0..10), threads 128..255 the high half (4q+2,4q+3, float4s 10..20).
// h is wave-uniform; all score indices compile-time. 11 independent float4
// loads/thread. Plain partial stores, no atomics.
__global__ void __launch_bounds__(256) k_pass2(const float* __restrict__ gt,
                                               const float* __restrict__ priors,
                                               const u64* __restrict__ bk,
                                               const u8* __restrict__ bidx,
                                               const float* __restrict__ loc_preds,
                                               const float* __restrict__ scores,
                                               float* __restrict__ mine,
                                               double* __restrict__ pl,
                                               double* __restrict__ pc,
                                               int* __restrict__ pn) {
    const int b = blockIdx.y;
    __shared__ float s_gt[O * 5];
    __shared__ int s_bp[O];
    const int tid = threadIdx.x;
    if (tid < O * 5) s_gt[tid] = gt[b * O * 5 + tid];
    if (tid < O) {
        u64 k = bk[((size_t)b * O + tid) * NB1];
#pragma unroll
        for (int i = 1; i < NB1; i++) {
            u64 v = bk[((size_t)b * O + tid) * NB1 + i];
            k = (v > k) ? v : k;
        }
        s_bp[tid] = (int)(0xFFFFFFFFu - (u32)(k & 0xFFFFFFFFull));
    }
    __syncthreads();

    const int h = tid >> 7;                       // wave-uniform half select
    const int qi = blockIdx.x * 128 + (tid & 127);
    float l_loc = 0.f, l_ce = 0.f;
    int l_np = 0;

    if (qi < QPI) {
        const float4* s4 = reinterpret_cast<const float4*>(scores)
                           + (size_t)b * (size_t)(P * NC / 4) + (size_t)21 * qi + h * 10;
        float fq[44];
#pragma unroll
        for (int i = 0; i < 11; i++) {
            float4 v = s4[i];
            fq[4 * i + 0] = v.x; fq[4 * i + 1] = v.y;
            fq[4 * i + 2] = v.z; fq[4 * i + 3] = v.w;
        }
        const int p0 = 4 * qi + 2 * h;
        const u32 mw = *reinterpret_cast<const unsigned short*>(bidx + (size_t)b * P + p0);
        const size_t lp_base = (size_t)b * P;

        float2 mv;
        if (h == 0) {
            // window = quad floats [0..43]: prior p0 at fq[0..20], p0+1 at fq[21..41]
            mv.x = prior_eval<0>(fq, s_gt, s_bp, p0, (int)(mw & 0xFFu),
                                 priors, loc_preds, lp_base, l_loc, l_ce, l_np);
            mv.y = prior_eval<21>(fq, s_gt, s_bp, p0 + 1, (int)(mw >> 8),
                                  priors, loc_preds, lp_base, l_loc, l_ce, l_np);
        } else {
            // window = quad floats [40..83]: prior p0 at fq[2..22], p0+1 at fq[23..43]
            mv.x = prior_eval<2>(fq, s_gt, s_bp, p0, (int)(mw & 0xFFu),
                                 priors, loc_preds, lp_base, l_loc, l_ce, l_np);
            mv.y = prior_eval<23>(fq, s_gt, s_bp, p0 + 1, (int)(mw >> 8),
                                  priors, loc_preds, lp_base, l_loc, l_ce, l_np);
        }
        *reinterpret_cast<float2*>(mine + (size_t)b * P + p0) = mv;
    }

    // wave shuffle reductions (float partials -> double at wave leader)
    const int lane = tid & 63;
    const int wave = tid >> 6;
#pragma unroll
    for (int off = 32; off > 0; off >>= 1) {
        l_loc += __shfl_xor(l_loc, off, 64);
        l_ce  += __shfl_xor(l_ce, off, 64);
        l_np  += __shfl_xor(l_np, off, 64);
    }
    __shared__ double s_loc[4], s_ce[4];
    __shared__ int s_np[4];
    if (lane == 0) { s_loc[wave] = (double)l_loc; s_ce[wave] = (double)l_ce; s_np[wave] = l_np; }
    __syncthreads();
    if (tid == 0) {
        int q = b * NBX + blockIdx.x;
        pl[q] = (s_loc[0] + s_loc[1]) + (s_loc[2] + s_loc[3]);
        pc[q] = (s_ce[0] + s_ce[1]) + (s_ce[2] + s_ce[3]);
        pn[q] = s_np[0] + s_np[1] + s_np[2] + s_np[3];
    }
}

// Hard-negative top-k sum with fused finalize. Each block self-computes
// total_pos, adds its neg-sum to acc[0] (128 atomics total), and the last
// block (ticket) sums pl/pc/pn (prior-kernel data, safe plain reads) and
// writes both outputs.
__global__ void __launch_bounds__(1024) k_hardneg(const float* __restrict__ mine,
                                                  const double* __restrict__ pl,
                                                  const double* __restrict__ pc,
                                                  const int* __restrict__ pn,
                                                  double* __restrict__ acc,
                                                  u32* __restrict__ ticket,
                                                  float* __restrict__ out) {
    const int b = blockIdx.x;
    const int tid = threadIdx.x;
    const int lane = tid & 63, wave = tid >> 6;
    __shared__ float s_mine[P];
    __shared__ u32 s_hist[256];
    __shared__ u32 s_sel[2];
    __shared__ double s_red[16];
    __shared__ int s_ti[16];
    __shared__ int s_k, s_tp;

    {
        int t = 0;
        for (int i = tid; i < NPART; i += 1024) t += pn[i];
#pragma unroll
        for (int off = 32; off > 0; off >>= 1) t += __shfl_xor(t, off, 64);
        if (lane == 0) s_ti[wave] = t;
    }
    __syncthreads();
    if (tid == 0) {
        int tp = 0;
#pragma unroll
        for (int w = 0; w < 16; w++) tp += s_ti[w];
        int np = 0;
        for (int x = 0; x < NBX; x++) np += pn[b * NBX + x];
        int k = 3 * np;
        int cap = P - tp - 1;
        if (cap < k) k = cap;
        s_k = k;
        s_tp = tp;
    }
    __syncthreads();
    const int k = s_k;

    if (k > 0) {
        for (int i = tid; i < P; i += 1024) s_mine[i] = mine[(size_t)b * P + i];
        if (tid == 0) { s_sel[0] = 0u; s_sel[1] = (u32)k; }
        __syncthreads();

        for (int shift = 24; shift >= 0; shift -= 8) {
            if (tid < 256) s_hist[tid] = 0u;
            __syncthreads();
            u32 prefix = s_sel[0];
            u32 kr = s_sel[1];
            u32 himask = (shift == 24) ? 0u : (0xFFFFFFFFu << (shift + 8));
            for (int i = tid; i < P; i += 1024) {
                u32 v = __float_as_uint(s_mine[i]);
                if ((v & himask) == prefix) atomicAdd(&s_hist[(v >> shift) & 255u], 1u);
            }
            __syncthreads();
            if (tid < 64) {
                const int L = tid;
                const int btop = 255 - 4 * L;
                u32 h0 = s_hist[btop], h1 = s_hist[btop - 1], h2 = s_hist[btop - 2], h3 = s_hist[btop - 3];
                u32 g4 = h0 + h1 + h2 + h3;
                u32 x = g4;
#pragma unroll
                for (int off = 1; off < 64; off <<= 1) {
                    u32 v = __shfl_up(x, off, 64);
                    if (L >= off) x += v;
                }
                u32 excl = x - g4;
                if (excl < kr && excl + g4 >= kr) {
                    u32 c = excl; int chosen = btop; u32 kloc = kr;
                    u32 nc;
                    nc = c + h0; if (c < kr && nc >= kr) { chosen = btop;     kloc = kr - c; } c = nc;
                    nc = c + h1; if (c < kr && nc >= kr) { chosen = btop - 1; kloc = kr - c; } c = nc;
                    nc = c + h2; if (c < kr && nc >= kr) { chosen = btop - 2; kloc = kr - c; } c = nc;
                    nc = c + h3; if (c < kr && nc >= kr) { chosen = btop - 3; kloc = kr - c; } c = nc;
                    s_sel[0] = prefix | ((u32)chosen << shift);
                    s_sel[1] = kloc;
                }
            }
            __syncthreads();
        }

        u32 tbits = s_sel[0];
        u32 kr = s_sel[1];
        float T = __uint_as_float(tbits);

        double sd = 0.0;
        for (int i = tid; i < P; i += 1024) {
            u32 v = __float_as_uint(s_mine[i]);
            if (v > tbits) sd += (double)s_mine[i];
        }
#pragma unroll
        for (int off = 32; off > 0; off >>= 1) sd += __shfl_xor(sd, off, 64);
        if (lane == 0) s_red[wave] = sd;
        __syncthreads();
        if (tid == 0) {
            double tt = 0.0;
#pragma unroll
            for (int w = 0; w < 16; w++) tt += s_red[w];
            atomicAdd(&acc[0], tt + (double)kr * (double)T);
        }
    }

    // fused finalize
    __threadfence();
    __syncthreads();
    __shared__ int s_last;
    if (tid == 0) s_last = (atomicAdd(ticket, 1u) == B - 1) ? 1 : 0;
    __syncthreads();
    if (s_last) {
        __shared__ double f_l[16], f_c[16];
        double tl = 0.0, tc = 0.0;
        for (int i = tid; i < NPART; i += 1024) { tl += pl[i]; tc += pc[i]; }
#pragma unroll
        for (int off = 32; off > 0; off >>= 1) {
            tl += __shfl_xor(tl, off, 64);
            tc += __shfl_xor(tc, off, 64);
        }
        if (lane == 0) { f_l[wave] = tl; f_c[wave] = tc; }
        __syncthreads();
        if (tid == 0) {
            double al = 0.0, ac = 0.0;
#pragma unroll
            for (int w = 0; w < 16; w++) { al += f_l[w]; ac += f_c[w]; }
            __threadfence();
            double ag = atomicAdd(&acc[0], 0.0);
            double n = (double)s_tp;
            out[0] = (float)(al / n);
            out[1] = (float)((ac + ag) / n);
        }
    }
}

extern "C" void kernel_launch(void* const* d_in, const int* in_sizes, int n_in,
                              void* d_out, int out_size, void* d_ws, size_t ws_size,
                              hipStream_t stream) {
    const float* loc_preds = (const float*)d_in[0];
    const float* scores    = (const float*)d_in[1];
    const float* gt        = (const float*)d_in[2];
    const float* priors    = (const float*)d_in[3];

    char* ws = (char*)d_ws;
    u64* bk      = (u64*)ws;                  // [0, 131072)        B*O*NB1 u64
    double* pl   = (double*)(ws + 131072);    // [131072, 149504)   NPART=2304 dbl
    double* pc   = (double*)(ws + 149504);    // [149504, 167936)
    int* pn      = (int*)(ws + 167936);       // [167936, 177152)
    double* acc  = (double*)(ws + 177152);    // [177152, 177160)   neg-sum
    u32* ticket  = (u32*)(ws + 177160);       // [177160, 177164)
    u8* bidx     = (u8*)(ws + 177168);        // [177168, 1294864)  B*P u8
    float* mine  = (float*)(ws + 1294880);    // B*P*4 (16B-aligned)

    k_pass1<<<dim3(NB1, B), dim3(256), 0, stream>>>(gt, priors, bk, bidx, acc, ticket);
    k_pass2<<<dim3(NBX, B), dim3(256), 0, stream>>>(
        gt, priors, bk, bidx, loc_preds, scores, mine, pl, pc, pn);
    k_hardneg<<<dim3(B), dim3(1024), 0, stream>>>(mine, pl, pc, pn, acc, ticket,
                                                  (float*)d_out);
}

// Round 15
// 62.379 us; speedup vs baseline: 1.4040x; 1.4040x over previous
//
#include <hip/hip_runtime.h>
#include <cstdint>
#include <cstddef>

#define B 128
#define P 8732
#define NC 21
#define O 16
#define THRESH 0.5f
#define NB1 8      // pass1 blocks per image
#define NBX2 12    // pass2 blocks per image
#define BPB 736    // priors per pass2 block (mult of 4)
#define WPW 184    // priors per wave (mult of 4)
#define NPART (B * NBX2)
#define SLABF 768  // padded slab floats: 3 DMA instrs x 64 lanes x 4 floats

typedef unsigned long long u64;
typedef unsigned int u32;
typedef unsigned char u8;

__device__ __forceinline__ float iou_pt(float a0, float a1, float a2, float a3,
                                        float b0, float b1, float b2, float b3) {
    float ltx = fmaxf(a0, b0), lty = fmaxf(a1, b1);
    float rbx = fminf(a2, b2), rby = fminf(a3, b3);
    float wx = fmaxf(rbx - ltx, 0.0f), wy = fmaxf(rby - lty, 0.0f);
    float inter = wx * wy;
    float aa = (a2 - a0) * (a3 - a1);
    float ab = (b2 - b0) * (b3 - b1);
    return inter / (aa + ab - inter);
}

// Pass 1: per-object best-prior partial max (plain stores) AND per-prior
// packed best-truth byte: idx | (ov>=THRESH ? 0x80 : 0).
__global__ void __launch_bounds__(256) k_pass1(const float* __restrict__ gt,
                                               const float* __restrict__ priors,
                                               u64* __restrict__ bk,
                                               u8* __restrict__ bidx) {
    const int b = blockIdx.y;
    __shared__ float s_gt[O * 4];
    __shared__ u64 s_wk[4][O];
    const int tid = threadIdx.x;
    const int wave = tid >> 6, lane = tid & 63;
    if (tid < O * 4) {
        int o = tid >> 2, c = tid & 3;
        s_gt[tid] = gt[(b * O + o) * 5 + c];
    }
    __syncthreads();

    u64 lk[O];
#pragma unroll
    for (int o = 0; o < O; o++) lk[o] = 0ull;

    for (int p = blockIdx.x * 256 + tid; p < P; p += NB1 * 256) {
        float4 pr = reinterpret_cast<const float4*>(priors)[p];
        float b0 = pr.x - pr.z * 0.5f, b1 = pr.y - pr.w * 0.5f;
        float b2 = pr.x + pr.z * 0.5f, b3 = pr.y + pr.w * 0.5f;
        float bov = -1.0f; int bo = 0;
#pragma unroll
        for (int o = 0; o < O; o++) {
            float v = iou_pt(s_gt[o * 4 + 0], s_gt[o * 4 + 1], s_gt[o * 4 + 2], s_gt[o * 4 + 3],
                             b0, b1, b2, b3);
            u64 key = ((u64)__float_as_uint(v) << 32) | (u64)(0xFFFFFFFFu - (u32)p);
            lk[o] = (key > lk[o]) ? key : lk[o];
            if (v > bov) { bov = v; bo = o; }   // first occurrence on tie
        }
        bidx[(size_t)b * P + p] = (u8)(bo | ((bov >= THRESH) ? 0x80 : 0));
    }

#pragma unroll
    for (int o = 0; o < O; o++) {
        u64 k = lk[o];
#pragma unroll
        for (int off = 32; off > 0; off >>= 1) {
            u64 other = (u64)__shfl_xor((long long)k, off, 64);
            k = (other > k) ? other : k;
        }
        if (lane == 0) s_wk[wave][o] = k;
    }
    __syncthreads();
    if (tid < O) {
        u64 k = s_wk[0][tid];
#pragma unroll
        for (int w = 1; w < 4; w++) { u64 v = s_wk[w][tid]; k = (v > k) ? v : k; }
        bk[((size_t)b * O + tid) * NB1 + blockIdx.x] = k;
    }
}

// Stage one 32-prior score chunk (nv*21/4 float4, nv mult of 4) into a
// wave-private padded LDS slab via global_load_lds DMA. All 3 instructions
// always issue with all lanes (vmcnt exact). LDS dest = base+lane*16
// unconditionally -> slab padded to 3*1024 B; clamped global sources stay
// in-bounds; pad is never read.
__device__ __forceinline__ void stage32(const float* __restrict__ gsrc,
                                        float* lds, int nf4, int lane) {
    const char* src = (const char*)gsrc;
    char* dst = (char*)lds;
#pragma unroll
    for (int i = 0; i < 3; i++) {
        int idx = i * 64 + lane;
        if (idx >= nf4) idx = nf4 - 1;
        __builtin_amdgcn_global_load_lds(
            (const __attribute__((address_space(1))) u32*)(src + (size_t)idx * 16),
            (__attribute__((address_space(3))) u32*)(dst + i * 1024),
            16, 0, 0);
    }
}

// Pass 2: wave-synchronous double-buffered DMA pipeline, 32-prior chunks,
// TWO LANES PER PRIOR (half the classes each, one shfl_xor(1) combine).
// 6.1 KB LDS/wave -> 6 blocks/CU -> 24 waves/CU (2x R12). No atomics.
__global__ void __launch_bounds__(256) k_pass2(const float* __restrict__ gt,
                                               const float* __restrict__ priors,
                                               const u64* __restrict__ bk,
                                               const u8* __restrict__ bidx,
                                               const float* __restrict__ loc_preds,
                                               const float* __restrict__ scores,
                                               float* __restrict__ mine,
                                               double* __restrict__ pl,
                                               double* __restrict__ pc,
                                               int* __restrict__ pn) {
    const int b = blockIdx.y;
    const int tid = threadIdx.x;
    const int wave = tid >> 6, lane = tid & 63;
    const int half = lane & 1;            // which class-half this lane owns
    __shared__ float s_slab[4][2][SLABF]; // 4 waves x 2 bufs x padded slab
    __shared__ float s_gt[O * 5];
    __shared__ int s_bp[O];

    if (tid < O * 5) s_gt[tid] = gt[b * O * 5 + tid];
    if (tid < O) {
        u64 k = bk[((size_t)b * O + tid) * NB1];
#pragma unroll
        for (int i = 1; i < NB1; i++) {
            u64 v = bk[((size_t)b * O + tid) * NB1 + i];
            k = (v > k) ? v : k;
        }
        s_bp[tid] = (int)(0xFFFFFFFFu - (u32)(k & 0xFFFFFFFFull));
    }
    __syncthreads();

    const int wbase = blockIdx.x * BPB + wave * WPW;
    int wp = P - wbase; if (wp > WPW) wp = WPW;
    const int nchunk = (wp > 0) ? ((wp + 31) >> 5) : 0;

    float l_loc = 0.f, l_ce = 0.f;
    int l_np = 0;

    if (nchunk > 0) {
        {
            int nv0 = wp < 32 ? wp : 32;
            stage32(scores + ((size_t)b * P + wbase) * NC,
                    &s_slab[wave][0][0], nv0 * 21 / 4, lane);
        }
        for (int c = 0; c < nchunk; ++c) {
            const int base = wbase + c * 32;
            int nv = wp - c * 32; if (nv > 32) nv = 32;   // mult of 4

            if (c + 1 < nchunk) {
                int nv2 = wp - (c + 1) * 32; if (nv2 > 32) nv2 = 32;
                asm volatile("s_waitcnt lgkmcnt(0)" ::: "memory");
                stage32(scores + ((size_t)b * P + base + 32) * NC,
                        &s_slab[wave][(c + 1) & 1][0], nv2 * 21 / 4, lane);
                asm volatile("s_waitcnt vmcnt(3)" ::: "memory");   // chunk c landed
            } else {
                asm volatile("s_waitcnt vmcnt(0)" ::: "memory");
            }
            __builtin_amdgcn_sched_barrier(0);

            const int pi = lane >> 1;          // prior index within chunk
            if (pi < nv) {
                const int p = base + pi;
                // this lane's class window: half0 -> [0..10], half1 -> [11..20]
                const float* sl = &s_slab[wave][c & 1][pi * NC + 11 * half];
                float v[11];
#pragma unroll
                for (int i = 0; i < 11; i++) v[i] = sl[i];
                const bool last_ok = (half == 0);   // half1 slot 10 is invalid

                int e = (int)bidx[(size_t)b * P + p];
                int best_idx = e & 0x3F;
                bool matched = (e & 0x80) != 0;
#pragma unroll
                for (int o = 0; o < O; o++) {
                    if (s_bp[o] == p) { best_idx = o; matched = true; }   // last wins
                }
                int cls = matched ? (int)s_gt[best_idx * 5 + 4] : 0;

                // half-max
                float pm = v[0];
#pragma unroll
                for (int i = 1; i < 10; i++) pm = fmaxf(pm, v[i]);
                pm = fmaxf(pm, last_ok ? v[10] : -1e30f);
                float m = fmaxf(pm, __shfl_xor(pm, 1, 64));

                // half exp-sum
                float ps = 0.f;
#pragma unroll
                for (int i = 0; i < 10; i++) ps += __expf(v[i] - m);
                ps += last_ok ? __expf(v[10] - m) : 0.f;
                float tot = ps + __shfl_xor(ps, 1, 64);
                float lse = m + __logf(tot);

                // half gather of class cls (exactly one lane contributes)
                float gp = 0.f;
#pragma unroll
                for (int i = 0; i < 11; i++) {
                    int cc = 11 * half + i;
                    gp += (cc == cls && (i < 10 || last_ok)) ? v[i] : 0.f;
                }
                float g = gp + __shfl_xor(gp, 1, 64);
                float ce = lse - g;

                if (half == 0) {
                    mine[(size_t)b * P + p] = matched ? 0.0f : ce;
                    if (matched) {   // matched <=> positive
                        l_np++;
                        l_ce += ce;
                        float4 pr = reinterpret_cast<const float4*>(priors)[p];
                        float m0 = s_gt[best_idx * 5 + 0], m1 = s_gt[best_idx * 5 + 1];
                        float m2 = s_gt[best_idx * 5 + 2], m3 = s_gt[best_idx * 5 + 3];
                        float tx = ((m0 + m2) * 0.5f - pr.x) / (0.1f * pr.z);
                        float ty = ((m1 + m3) * 0.5f - pr.y) / (0.1f * pr.w);
                        float tw = __logf((m2 - m0) / pr.z) * 5.0f;
                        float th = __logf((m3 - m1) / pr.w) * 5.0f;
                        float4 lp = reinterpret_cast<const float4*>(loc_preds)[(size_t)b * P + p];
                        float d0 = fabsf(lp.x - tx), d1 = fabsf(lp.y - ty);
                        float d2 = fabsf(lp.z - tw), d3 = fabsf(lp.w - th);
                        float s0 = d0 < 1.0f ? 0.5f * d0 * d0 : d0 - 0.5f;
                        float s1 = d1 < 1.0f ? 0.5f * d1 * d1 : d1 - 0.5f;
                        float s2 = d2 < 1.0f ? 0.5f * d2 * d2 : d2 - 0.5f;
                        float s3 = d3 < 1.0f ? 0.5f * d3 * d3 : d3 - 0.5f;
                        l_loc += (s0 + s1) + (s2 + s3);
                    }
                }
            }
        }
    }

    // wave shuffle reductions -> plain partial stores
#pragma unroll
    for (int off = 32; off > 0; off >>= 1) {
        l_loc += __shfl_xor(l_loc, off, 64);
        l_ce  += __shfl_xor(l_ce, off, 64);
        l_np  += __shfl_xor(l_np, off, 64);
    }
    __shared__ double s_loc[4], s_ce[4];
    __shared__ int s_np[4];
    if (lane == 0) { s_loc[wave] = (double)l_loc; s_ce[wave] = (double)l_ce; s_np[wave] = l_np; }
    __syncthreads();
    if (tid == 0) {
        int q = b * NBX2 + blockIdx.x;
        pl[q] = (s_loc[0] + s_loc[1]) + (s_loc[2] + s_loc[3]);
        pc[q] = (s_ce[0] + s_ce[1]) + (s_ce[2] + s_ce[3]);
        pn[q] = s_np[0] + s_np[1] + s_np[2] + s_np[3];
    }
}

// Hard-negative top-k sum; self-computes total_pos; plain stores; no atomics.
__global__ void __launch_bounds__(1024) k_hardneg(const float* __restrict__ mine,
                                                  const int* __restrict__ pn,
                                                  double* __restrict__ pneg) {
    const int b = blockIdx.x;
    const int tid = threadIdx.x;
    const int lane = tid & 63, wave = tid >> 6;
    __shared__ float s_mine[P];
    __shared__ u32 s_hist[256];
    __shared__ u32 s_sel[2];
    __shared__ double s_red[16];
    __shared__ int s_ti[16];
    __shared__ int s_npx[NBX2];
    __shared__ int s_k;

    {
        int t = 0;
        for (int i = tid; i < NPART; i += 1024) t += pn[i];
#pragma unroll
        for (int off = 32; off > 0; off >>= 1) t += __shfl_xor(t, off, 64);
        if (lane == 0) s_ti[wave] = t;
    }
    if (tid < NBX2) s_npx[tid] = pn[b * NBX2 + tid];
    __syncthreads();
    if (tid == 0) {
        int tp = 0;
#pragma unroll
        for (int w = 0; w < 16; w++) tp += s_ti[w];
        int np = 0;
#pragma unroll
        for (int x = 0; x < NBX2; x++) np += s_npx[x];
        int k = 3 * np;
        int cap = P - tp - 1;
        if (cap < k) k = cap;
        s_k = k;
    }
    __syncthreads();
    const int k = s_k;

    if (k <= 0) {
        if (tid == 0) pneg[b] = 0.0;
        return;
    }

    for (int i = tid; i < P; i += 1024) s_mine[i] = mine[(size_t)b * P + i];
    if (tid == 0) { s_sel[0] = 0u; s_sel[1] = (u32)k; }
    __syncthreads();

    for (int shift = 24; shift >= 0; shift -= 8) {
        if (tid < 256) s_hist[tid] = 0u;
        __syncthreads();
        u32 prefix = s_sel[0];
        u32 kr = s_sel[1];
        u32 himask = (shift == 24) ? 0u : (0xFFFFFFFFu << (shift + 8));
        for (int i = tid; i < P; i += 1024) {
            u32 v = __float_as_uint(s_mine[i]);
            if ((v & himask) == prefix) atomicAdd(&s_hist[(v >> shift) & 255u], 1u);
        }
        __syncthreads();
        if (tid < 64) {
            const int L = tid;
            const int btop = 255 - 4 * L;
            u32 h0 = s_hist[btop], h1 = s_hist[btop - 1], h2 = s_hist[btop - 2], h3 = s_hist[btop - 3];
            u32 g4 = h0 + h1 + h2 + h3;
            u32 x = g4;
#pragma unroll
            for (int off = 1; off < 64; off <<= 1) {
                u32 v = __shfl_up(x, off, 64);
                if (L >= off) x += v;
            }
            u32 excl = x - g4;
            if (excl < kr && excl + g4 >= kr) {
                u32 c = excl; int chosen = btop; u32 kloc = kr;
                u32 nc;
                nc = c + h0; if (c < kr && nc >= kr) { chosen = btop;     kloc = kr - c; } c = nc;
                nc = c + h1; if (c < kr && nc >= kr) { chosen = btop - 1; kloc = kr - c; } c = nc;
                nc = c + h2; if (c < kr && nc >= kr) { chosen = btop - 2; kloc = kr - c; } c = nc;
                nc = c + h3; if (c < kr && nc >= kr) { chosen = btop - 3; kloc = kr - c; } c = nc;
                s_sel[0] = prefix | ((u32)chosen << shift);
                s_sel[1] = kloc;
            }
        }
        __syncthreads();
    }

    u32 tbits = s_sel[0];
    u32 kr = s_sel[1];
    float T = __uint_as_float(tbits);

    double sd = 0.0;
    for (int i = tid; i < P; i += 1024) {
        u32 v = __float_as_uint(s_mine[i]);
        if (v > tbits) sd += (double)s_mine[i];
    }
#pragma unroll
    for (int off = 32; off > 0; off >>= 1) sd += __shfl_xor(sd, off, 64);
    if (lane == 0) s_red[wave] = sd;
    __syncthreads();
    if (tid == 0) {
        double tt = 0.0;
#pragma unroll
        for (int w = 0; w < 16; w++) tt += s_red[w];
        pneg[b] = tt + (double)kr * (double)T;
    }
}

// Final: sum all partials, write both outputs.
__global__ void __launch_bounds__(1024) k_fin(const double* __restrict__ pl,
                                              const double* __restrict__ pc,
                                              const int* __restrict__ pn,
                                              const double* __restrict__ pneg,
                                              float* __restrict__ out) {
    const int tid = threadIdx.x;
    const int lane = tid & 63, wave = tid >> 6;
    __shared__ double s_l[16], s_c[16], s_g[16];
    __shared__ int s_t[16];

    double tl = 0.0, tc = 0.0, tg = 0.0;
    int tn = 0;
    for (int i = tid; i < NPART; i += 1024) { tl += pl[i]; tc += pc[i]; tn += pn[i]; }
    if (tid < B) tg = pneg[tid];
#pragma unroll
    for (int off = 32; off > 0; off >>= 1) {
        tl += __shfl_xor(tl, off, 64);
        tc += __shfl_xor(tc, off, 64);
        tg += __shfl_xor(tg, off, 64);
        tn += __shfl_xor(tn, off, 64);
    }
    if (lane == 0) { s_l[wave] = tl; s_c[wave] = tc; s_g[wave] = tg; s_t[wave] = tn; }
    __syncthreads();
    if (tid == 0) {
        double al = 0.0, ac = 0.0, ag = 0.0;
        int an = 0;
#pragma unroll
        for (int w = 0; w < 16; w++) { al += s_l[w]; ac += s_c[w]; ag += s_g[w]; an += s_t[w]; }
        double n = (double)an;
        out[0] = (float)(al / n);
        out[1] = (float)((ac + ag) / n);
    }
}

extern "C" void kernel_launch(void* const* d_in, const int* in_sizes, int n_in,
                              void* d_out, int out_size, void* d_ws, size_t ws_size,
                              hipStream_t stream) {
    const float* loc_preds = (const float*)d_in[0];
    const float* scores    = (const float*)d_in[1];
    const float* gt        = (const float*)d_in[2];
    const float* priors    = (const float*)d_in[3];

    char* ws = (char*)d_ws;
    u64* bk      = (u64*)ws;                  // [0, 131072)        B*O*NB1 u64
    double* pl   = (double*)(ws + 131072);    // [131072, 143360)   NPART=1536 dbl
    double* pc   = (double*)(ws + 143360);    // [143360, 155648)
    int* pn      = (int*)(ws + 155648);       // [155648, 161792)
    double* pneg = (double*)(ws + 161792);    // [161792, 162816)
    u8* bidx     = (u8*)(ws + 162816);        // [162816, 1280512)  B*P u8
    float* mine  = (float*)(ws + 1280512);    // B*P*4 (16B-aligned)

    // no memset needed: every ws slot consumed is plainly overwritten each call

    k_pass1<<<dim3(NB1, B), dim3(256), 0, stream>>>(gt, priors, bk, bidx);
    k_pass2<<<dim3(NBX2, B), dim3(256), 0, stream>>>(
        gt, priors, bk, bidx, loc_preds, scores, mine, pl, pc, pn);
    k_hardneg<<<dim3(B), dim3(1024), 0, stream>>>(mine, pn, pneg);
    k_fin<<<dim3(1), dim3(1024), 0, stream>>>(pl, pc, pn, pneg, (float*)d_out);
}

// Round 16
// 60.988 us; speedup vs baseline: 1.4360x; 1.0228x over previous
//
#include <hip/hip_runtime.h>
#include <cstdint>
#include <cstddef>

#define B 128
#define P 8732
#define NC 21
#define O 16
#define THRESH 0.5f
#define NB1 8      // pass1 blocks per image
#define NBX2 4     // pass2 blocks per image
#define BPB 2304   // priors per pass2 block
#define WPW 576    // priors per wave (multiple of 64)
#define NPART (B * NBX2)
#define SLABF 1536 // padded slab floats: 6 DMA instrs x 64 lanes x 4 floats

typedef unsigned long long u64;
typedef unsigned int u32;
typedef unsigned char u8;

__device__ __forceinline__ float iou_pt(float a0, float a1, float a2, float a3,
                                        float b0, float b1, float b2, float b3) {
    float ltx = fmaxf(a0, b0), lty = fmaxf(a1, b1);
    float rbx = fminf(a2, b2), rby = fminf(a3, b3);
    float wx = fmaxf(rbx - ltx, 0.0f), wy = fmaxf(rby - lty, 0.0f);
    float inter = wx * wy;
    float aa = (a2 - a0) * (a3 - a1);
    float ab = (b2 - b0) * (b3 - b1);
    return inter / (aa + ab - inter);
}

// Pass 1: per-object best-prior partial max (plain stores) AND per-prior
// packed best-truth byte: idx | (ov>=THRESH ? 0x80 : 0).
__global__ void __launch_bounds__(256) k_pass1(const float* __restrict__ gt,
                                               const float* __restrict__ priors,
                                               u64* __restrict__ bk,
                                               u8* __restrict__ bidx) {
    const int b = blockIdx.y;
    __shared__ float s_gt[O * 4];
    __shared__ u64 s_wk[4][O];
    const int tid = threadIdx.x;
    const int wave = tid >> 6, lane = tid & 63;
    if (tid < O * 4) {
        int o = tid >> 2, c = tid & 3;
        s_gt[tid] = gt[(b * O + o) * 5 + c];
    }
    __syncthreads();

    u64 lk[O];
#pragma unroll
    for (int o = 0; o < O; o++) lk[o] = 0ull;

    for (int p = blockIdx.x * 256 + tid; p < P; p += NB1 * 256) {
        float4 pr = reinterpret_cast<const float4*>(priors)[p];
        float b0 = pr.x - pr.z * 0.5f, b1 = pr.y - pr.w * 0.5f;
        float b2 = pr.x + pr.z * 0.5f, b3 = pr.y + pr.w * 0.5f;
        float bov = -1.0f; int bo = 0;
#pragma unroll
        for (int o = 0; o < O; o++) {
            float v = iou_pt(s_gt[o * 4 + 0], s_gt[o * 4 + 1], s_gt[o * 4 + 2], s_gt[o * 4 + 3],
                             b0, b1, b2, b3);
            u64 key = ((u64)__float_as_uint(v) << 32) | (u64)(0xFFFFFFFFu - (u32)p);
            lk[o] = (key > lk[o]) ? key : lk[o];
            if (v > bov) { bov = v; bo = o; }   // first occurrence on tie
        }
        bidx[(size_t)b * P + p] = (u8)(bo | ((bov >= THRESH) ? 0x80 : 0));
    }

#pragma unroll
    for (int o = 0; o < O; o++) {
        u64 k = lk[o];
#pragma unroll
        for (int off = 32; off > 0; off >>= 1) {
            u64 other = (u64)__shfl_xor((long long)k, off, 64);
            k = (other > k) ? other : k;
        }
        if (lane == 0) s_wk[wave][o] = k;
    }
    __syncthreads();
    if (tid < O) {
        u64 k = s_wk[0][tid];
#pragma unroll
        for (int w = 1; w < 4; w++) { u64 v = s_wk[w][tid]; k = (v > k) ? v : k; }
        bk[((size_t)b * O + tid) * NB1 + blockIdx.x] = k;
    }
}

// Stage one 64-prior score chunk into a wave-private padded LDS slab via
// global_load_lds DMA. All 6 instructions always issue with all lanes
// (vmcnt increments exact). LDS dest = base+lane*16 unconditionally ->
// slab padded to 6*1024 B; clamped global sources stay in-bounds; pad never
// read. nv is always a multiple of 4 (64 or 28) so nf4 is exact.
__device__ __forceinline__ void stage64(const float* __restrict__ gsrc,
                                        float* lds, int nf4, int lane) {
    const char* src = (const char*)gsrc;
    char* dst = (char*)lds;
#pragma unroll
    for (int i = 0; i < 6; i++) {
        int idx = i * 64 + lane;
        if (idx >= nf4) idx = nf4 - 1;
        __builtin_amdgcn_global_load_lds(
            (const __attribute__((address_space(1))) u32*)(src + (size_t)idx * 16),
            (__attribute__((address_space(3))) u32*)(dst + i * 1024),
            16, 0, 0);
    }
}

// Pass 2: wave-synchronous TRIPLE-buffered DMA pipeline, 2 chunks prefetched
// ahead (12 DMAs in flight) so the ~900-cycle HBM latency is fully covered by
// ~2 chunks of compute even when a block's waves run in lockstep (the convoy
// that capped VALUBusy at ~38% with the 1-ahead pipeline). vmcnt in-order
// retirement makes the counted waits exact. No atomics.
__global__ void __launch_bounds__(256) k_pass2(const float* __restrict__ gt,
                                               const float* __restrict__ priors,
                                               const u64* __restrict__ bk,
                                               const u8* __restrict__ bidx,
                                               const float* __restrict__ loc_preds,
                                               const float* __restrict__ scores,
                                               float* __restrict__ mine,
                                               double* __restrict__ pl,
                                               double* __restrict__ pc,
                                               int* __restrict__ pn) {
    const int b = blockIdx.y;
    const int tid = threadIdx.x;
    const int wave = tid >> 6, lane = tid & 63;
    __shared__ float s_slab[4][3][SLABF];   // 4 waves x 3 bufs x padded slab (73.7 KB)
    __shared__ float s_gt[O * 5];
    __shared__ int s_bp[O];

    if (tid < O * 5) s_gt[tid] = gt[b * O * 5 + tid];
    if (tid < O) {
        u64 k = bk[((size_t)b * O + tid) * NB1];
#pragma unroll
        for (int i = 1; i < NB1; i++) {
            u64 v = bk[((size_t)b * O + tid) * NB1 + i];
            k = (v > k) ? v : k;
        }
        s_bp[tid] = (int)(0xFFFFFFFFu - (u32)(k & 0xFFFFFFFFull));
    }
    __syncthreads();

    const int wbase = blockIdx.x * BPB + wave * WPW;
    int wp = P - wbase; if (wp > WPW) wp = WPW;   // multiples of 4 (P%64==28)
    const int nchunk = (wp > 0) ? ((wp + 63) >> 6) : 0;

    float l_loc = 0.f, l_ce = 0.f;
    int l_np = 0;

    if (nchunk > 0) {
        // prologue: stage up to 3 chunks
        for (int c0 = 0; c0 < 3 && c0 < nchunk; ++c0) {
            int nv0 = wp - c0 * 64; if (nv0 > 64) nv0 = 64;
            stage64(scores + ((size_t)b * P + wbase + c0 * 64) * NC,
                    &s_slab[wave][c0][0], nv0 * 21 / 4, lane);
        }
        for (int c = 0; c < nchunk; ++c) {
            const int base = wbase + c * 64;
            int nv = wp - c * 64; if (nv > 64) nv = 64;

            // chunk c landed when outstanding <= 6 * (chunks staged after c)
            int ahead = nchunk - 1 - c; if (ahead > 2) ahead = 2;
            if (ahead == 2)      asm volatile("s_waitcnt vmcnt(12)" ::: "memory");
            else if (ahead == 1) asm volatile("s_waitcnt vmcnt(6)" ::: "memory");
            else                 asm volatile("s_waitcnt vmcnt(0)" ::: "memory");
            __builtin_amdgcn_sched_barrier(0);

            if (lane < nv) {
                const int p = base + lane;
                const float* fsl = &s_slab[wave][c % 3][lane * NC];
                float fs[NC];
#pragma unroll
                for (int cc = 0; cc < NC; cc++) fs[cc] = fsl[cc];   // stride-21: 2-way bank = free

                int e = (int)bidx[(size_t)b * P + p];
                int best_idx = e & 0x3F;
                bool matched = (e & 0x80) != 0;
#pragma unroll
                for (int o = 0; o < O; o++) {
                    if (s_bp[o] == p) { best_idx = o; matched = true; }   // last wins
                }
                int cls = matched ? (int)s_gt[best_idx * 5 + 4] : 0;

                float mx = fs[0];
#pragma unroll
                for (int cc = 1; cc < NC; cc++) mx = fmaxf(mx, fs[cc]);
                float se = 0.0f;
#pragma unroll
                for (int cc = 0; cc < NC; cc++) se += __expf(fs[cc] - mx);
                float lse = mx + __logf(se);
                float g = fs[0];
#pragma unroll
                for (int cc = 1; cc < NC; cc++) g = (cc == cls) ? fs[cc] : g;
                float ce = lse - g;

                mine[(size_t)b * P + p] = matched ? 0.0f : ce;

                if (matched) {   // matched <=> positive (labels >= 1)
                    l_np++;
                    l_ce += ce;
                    float4 pr = reinterpret_cast<const float4*>(priors)[p];
                    float m0 = s_gt[best_idx * 5 + 0], m1 = s_gt[best_idx * 5 + 1];
                    float m2 = s_gt[best_idx * 5 + 2], m3 = s_gt[best_idx * 5 + 3];
                    float tx = ((m0 + m2) * 0.5f - pr.x) / (0.1f * pr.z);
                    float ty = ((m1 + m3) * 0.5f - pr.y) / (0.1f * pr.w);
                    float tw = __logf((m2 - m0) / pr.z) * 5.0f;
                    float th = __logf((m3 - m1) / pr.w) * 5.0f;
                    float4 lp = reinterpret_cast<const float4*>(loc_preds)[(size_t)b * P + p];
                    float d0 = fabsf(lp.x - tx), d1 = fabsf(lp.y - ty);
                    float d2 = fabsf(lp.z - tw), d3 = fabsf(lp.w - th);
                    float s0 = d0 < 1.0f ? 0.5f * d0 * d0 : d0 - 0.5f;
                    float s1 = d1 < 1.0f ? 0.5f * d1 * d1 : d1 - 0.5f;
                    float s2 = d2 < 1.0f ? 0.5f * d2 * d2 : d2 - 0.5f;
                    float s3 = d3 < 1.0f ? 0.5f * d3 * d3 : d3 - 0.5f;
                    l_loc += (s0 + s1) + (s2 + s3);
                }
            }

            // stage chunk c+3 into buf[c%3] (its reads were just consumed)
            if (c + 3 < nchunk) {
                int nv3 = wp - (c + 3) * 64; if (nv3 > 64) nv3 = 64;
                asm volatile("s_waitcnt lgkmcnt(0)" ::: "memory");
                stage64(scores + ((size_t)b * P + base + 3 * 64) * NC,
                        &s_slab[wave][c % 3][0], nv3 * 21 / 4, lane);
            }
        }
    }

    // wave shuffle reductions -> plain partial stores
#pragma unroll
    for (int off = 32; off > 0; off >>= 1) {
        l_loc += __shfl_xor(l_loc, off, 64);
        l_ce  += __shfl_xor(l_ce, off, 64);
        l_np  += __shfl_xor(l_np, off, 64);
    }
    __shared__ double s_loc[4], s_ce[4];
    __shared__ int s_np[4];
    if (lane == 0) { s_loc[wave] = (double)l_loc; s_ce[wave] = (double)l_ce; s_np[wave] = l_np; }
    __syncthreads();
    if (tid == 0) {
        int q = b * NBX2 + blockIdx.x;
        pl[q] = (s_loc[0] + s_loc[1]) + (s_loc[2] + s_loc[3]);
        pc[q] = (s_ce[0] + s_ce[1]) + (s_ce[2] + s_ce[3]);
        pn[q] = s_np[0] + s_np[1] + s_np[2] + s_np[3];
    }
}

// Hard-negative top-k sum; self-computes total_pos; plain stores; no atomics.
__global__ void __launch_bounds__(1024) k_hardneg(const float* __restrict__ mine,
                                                  const int* __restrict__ pn,
                                                  double* __restrict__ pneg) {
    const int b = blockIdx.x;
    const int tid = threadIdx.x;
    const int lane = tid & 63, wave = tid >> 6;
    __shared__ float s_mine[P];
    __shared__ u32 s_hist[256];
    __shared__ u32 s_sel[2];
    __shared__ double s_red[16];
    __shared__ int s_ti[16];
    __shared__ int s_npx[NBX2];
    __shared__ int s_k;

    {
        int t = 0;
        for (int i = tid; i < NPART; i += 1024) t += pn[i];
#pragma unroll
        for (int off = 32; off > 0; off >>= 1) t += __shfl_xor(t, off, 64);
        if (lane == 0) s_ti[wave] = t;
    }
    if (tid < NBX2) s_npx[tid] = pn[b * NBX2 + tid];
    __syncthreads();
    if (tid == 0) {
        int tp = 0;
#pragma unroll
        for (int w = 0; w < 16; w++) tp += s_ti[w];
        int np = 0;
#pragma unroll
        for (int x = 0; x < NBX2; x++) np += s_npx[x];
        int k = 3 * np;
        int cap = P - tp - 1;
        if (cap < k) k = cap;
        s_k = k;
    }
    __syncthreads();
    const int k = s_k;

    if (k <= 0) {
        if (tid == 0) pneg[b] = 0.0;
        return;
    }

    for (int i = tid; i < P; i += 1024) s_mine[i] = mine[(size_t)b * P + i];
    if (tid == 0) { s_sel[0] = 0u; s_sel[1] = (u32)k; }
    __syncthreads();

    for (int shift = 24; shift >= 0; shift -= 8) {
        if (tid < 256) s_hist[tid] = 0u;
        __syncthreads();
        u32 prefix = s_sel[0];
        u32 kr = s_sel[1];
        u32 himask = (shift == 24) ? 0u : (0xFFFFFFFFu << (shift + 8));
        for (int i = tid; i < P; i += 1024) {
            u32 v = __float_as_uint(s_mine[i]);
            if ((v & himask) == prefix) atomicAdd(&s_hist[(v >> shift) & 255u], 1u);
        }
        __syncthreads();
        if (tid < 64) {
            const int L = tid;
            const int btop = 255 - 4 * L;
            u32 h0 = s_hist[btop], h1 = s_hist[btop - 1], h2 = s_hist[btop - 2], h3 = s_hist[btop - 3];
            u32 g4 = h0 + h1 + h2 + h3;
            u32 x = g4;
#pragma unroll
            for (int off = 1; off < 64; off <<= 1) {
                u32 v = __shfl_up(x, off, 64);
                if (L >= off) x += v;
            }
            u32 excl = x - g4;
            if (excl < kr && excl + g4 >= kr) {
                u32 c = excl; int chosen = btop; u32 kloc = kr;
                u32 nc;
                nc = c + h0; if (c < kr && nc >= kr) { chosen = btop;     kloc = kr - c; } c = nc;
                nc = c + h1; if (c < kr && nc >= kr) { chosen = btop - 1; kloc = kr - c; } c = nc;
                nc = c + h2; if (c < kr && nc >= kr) { chosen = btop - 2; kloc = kr - c; } c = nc;
                nc = c + h3; if (c < kr && nc >= kr) { chosen = btop - 3; kloc = kr - c; } c = nc;
                s_sel[0] = prefix | ((u32)chosen << shift);
                s_sel[1] = kloc;
            }
        }
        __syncthreads();
    }

    u32 tbits = s_sel[0];
    u32 kr = s_sel[1];
    float T = __uint_as_float(tbits);

    double sd = 0.0;
    for (int i = tid; i < P; i += 1024) {
        u32 v = __float_as_uint(s_mine[i]);
        if (v > tbits) sd += (double)s_mine[i];
    }
#pragma unroll
    for (int off = 32; off > 0; off >>= 1) sd += __shfl_xor(sd, off, 64);
    if (lane == 0) s_red[wave] = sd;
    __syncthreads();
    if (tid == 0) {
        double tt = 0.0;
#pragma unroll
        for (int w = 0; w < 16; w++) tt += s_red[w];
        pneg[b] = tt + (double)kr * (double)T;
    }
}

// Final: sum all partials, write both outputs.
__global__ void __launch_bounds__(1024) k_fin(const double* __restrict__ pl,
                                              const double* __restrict__ pc,
                                              const int* __restrict__ pn,
                                              const double* __restrict__ pneg,
                                              float* __restrict__ out) {
    const int tid = threadIdx.x;
    const int lane = tid & 63, wave = tid >> 6;
    __shared__ double s_l[16], s_c[16], s_g[16];
    __shared__ int s_t[16];

    double tl = 0.0, tc = 0.0, tg = 0.0;
    int tn = 0;
    for (int i = tid; i < NPART; i += 1024) { tl += pl[i]; tc += pc[i]; tn += pn[i]; }
    if (tid < B) tg = pneg[tid];
#pragma unroll
    for (int off = 32; off > 0; off >>= 1) {
        tl += __shfl_xor(tl, off, 64);
        tc += __shfl_xor(tc, off, 64);
        tg += __shfl_xor(tg, off, 64);
        tn += __shfl_xor(tn, off, 64);
    }
    if (lane == 0) { s_l[wave] = tl; s_c[wave] = tc; s_g[wave] = tg; s_t[wave] = tn; }
    __syncthreads();
    if (tid == 0) {
        double al = 0.0, ac = 0.0, ag = 0.0;
        int an = 0;
#pragma unroll
        for (int w = 0; w < 16; w++) { al += s_l[w]; ac += s_c[w]; ag += s_g[w]; an += s_t[w]; }
        double n = (double)an;
        out[0] = (float)(al / n);
        out[1] = (float)((ac + ag) / n);
    }
}

extern "C" void kernel_launch(void* const* d_in, const int* in_sizes, int n_in,
                              void* d_out, int out_size, void* d_ws, size_t ws_size,
                              hipStream_t stream) {
    const float* loc_preds = (const float*)d_in[0];
    const float* scores    = (const float*)d_in[1];
    const float* gt        = (const float*)d_in[2];
    const float* priors    = (const float*)d_in[3];

    char* ws = (char*)d_ws;
    u64* bk      = (u64*)ws;                  // [0, 131072)        B*O*NB1 u64
    double* pl   = (double*)(ws + 131072);    // [131072, 135168)   NPART=512 dbl
    double* pc   = (double*)(ws + 135168);    // [135168, 139264)
    int* pn      = (int*)(ws + 139264);       // [139264, 141312)
    double* pneg = (double*)(ws + 141312);    // [141312, 142336)
    u8* bidx     = (u8*)(ws + 142336);        // [142336, 1260032)  B*P u8
    float* mine  = (float*)(ws + 1260032);    // B*P*4 (16B-aligned)

    // no memset needed: every ws slot consumed is plainly overwritten each call

    k_pass1<<<dim3(NB1, B), dim3(256), 0, stream>>>(gt, priors, bk, bidx);
    k_pass2<<<dim3(NBX2, B), dim3(256), 0, stream>>>(
        gt, priors, bk, bidx, loc_preds, scores, mine, pl, pc, pn);
    k_hardneg<<<dim3(B), dim3(1024), 0, stream>>>(mine, pn, pneg);
    k_fin<<<dim3(1), dim3(1024), 0, stream>>>(pl, pc, pn, pneg, (float*)d_out);
}